// Round 1
// baseline (663.024 us; speedup 1.0000x reference)
//
#include <hip/hip_runtime.h>
#include <math.h>

#define VOCAB   100000
#define EMBED   300
#define HIDDEN  300
#define BATCH   32768
#define K_NEG   10
#define EPSV    1e-5f

// ---------------------------------------------------------------------------
// GEMM: C[m,n] = sum_k A[rowsel(m),k] * W[n,k] + bias[n]
// A: [*,K] f32 (optionally row-gathered via idx), W: [N,K] f32, C: [M,N]
// Tiles: BM=64, BN=64, BK=16; 256 threads; 4x4 microtile per thread.
// ---------------------------------------------------------------------------
template <bool GATHER>
__global__ __launch_bounds__(256)
void gemm_at_kernel(const float* __restrict__ A, const int* __restrict__ idx,
                    const float* __restrict__ W, const float* __restrict__ bias,
                    float* __restrict__ C, int M, int N, int K)
{
    constexpr int BM = 64, BN = 64, BK = 16;
    __shared__ float As[BK][BM + 4];
    __shared__ float Ws[BK][BN + 4];

    const int tid = threadIdx.x;
    const int m0 = blockIdx.y * BM;
    const int n0 = blockIdx.x * BN;
    const int tx = tid & 15;   // micro-col group (4 cols)
    const int ty = tid >> 4;   // micro-row group (4 rows)

    float acc[4][4] = {};

    // Loader mapping: each thread loads 4 consecutive k for one row of A and
    // one row of W per BK chunk.
    const int lm = tid >> 2;          // 0..63 : row within tile
    const int lk = (tid & 3) * 4;     // 0,4,8,12 : k offset within chunk

    const int arow  = m0 + lm;                       // M=32768, always in range
    const int agrow = GATHER ? idx[arow] : arow;
    const float* aptr = A + (size_t)agrow * K;

    const int wn = n0 + lm;
    const float* wptr = (wn < N) ? (W + (size_t)wn * K) : nullptr;

    for (int k0 = 0; k0 < K; k0 += BK) {
        const int kk = k0 + lk;
        float4 av = make_float4(0.f, 0.f, 0.f, 0.f);
        if (kk + 3 < K) {
            av = *(const float4*)(aptr + kk);
        } else {
            float t[4] = {0.f, 0.f, 0.f, 0.f};
            for (int j = 0; j < 4; ++j) if (kk + j < K) t[j] = aptr[kk + j];
            av = make_float4(t[0], t[1], t[2], t[3]);
        }
        float4 wv = make_float4(0.f, 0.f, 0.f, 0.f);
        if (wptr) {
            if (kk + 3 < K) {
                wv = *(const float4*)(wptr + kk);
            } else {
                float t[4] = {0.f, 0.f, 0.f, 0.f};
                for (int j = 0; j < 4; ++j) if (kk + j < K) t[j] = wptr[kk + j];
                wv = make_float4(t[0], t[1], t[2], t[3]);
            }
        }
        __syncthreads();   // previous iteration's LDS reads complete
        As[lk + 0][lm] = av.x; As[lk + 1][lm] = av.y;
        As[lk + 2][lm] = av.z; As[lk + 3][lm] = av.w;
        Ws[lk + 0][lm] = wv.x; Ws[lk + 1][lm] = wv.y;
        Ws[lk + 2][lm] = wv.z; Ws[lk + 3][lm] = wv.w;
        __syncthreads();

        #pragma unroll
        for (int k = 0; k < BK; ++k) {
            float a[4], w[4];
            #pragma unroll
            for (int i = 0; i < 4; ++i) a[i] = As[k][ty * 4 + i];
            #pragma unroll
            for (int j = 0; j < 4; ++j) w[j] = Ws[k][tx * 4 + j];
            #pragma unroll
            for (int i = 0; i < 4; ++i)
                #pragma unroll
                for (int j = 0; j < 4; ++j)
                    acc[i][j] = fmaf(a[i], w[j], acc[i][j]);
        }
    }

    #pragma unroll
    for (int i = 0; i < 4; ++i) {
        const int m = m0 + ty * 4 + i;
        #pragma unroll
        for (int j = 0; j < 4; ++j) {
            const int n = n0 + tx * 4 + j;
            if (n < N) C[(size_t)m * N + n] = acc[i][j] + bias[n];
        }
    }
}

// ---------------------------------------------------------------------------
// Per-row loss: one wave (64 lanes) per batch row.
//  - logits = enc_row . W_cls[0/1] + b_cls  -> 2-class CE (log_softmax nll)
//  - pos = softplus(-clip(center_v . ctx_v))
//  - neg = sum_k softplus(clip(center_v . neg_v_k))
// Block-level partial sums -> one global atomicAdd pair per block.
// ---------------------------------------------------------------------------
__device__ inline float wave_red(float v) {
    #pragma unroll
    for (int o = 32; o; o >>= 1) v += __shfl_down(v, o);
    return v;
}
__device__ inline float softplusf(float x) {
    // log(1+exp(x)), stable
    return x > 0.f ? x + log1pf(expf(-x)) : log1pf(expf(x));
}

__global__ __launch_bounds__(256)
void loss_kernel(const float* __restrict__ enc, const float* __restrict__ center_v,
                 const int* __restrict__ ctx_ids, const int* __restrict__ neg_ids,
                 const int* __restrict__ labels,
                 const float* __restrict__ context_emb,
                 const float* __restrict__ W_cls, const float* __restrict__ b_cls,
                 float* __restrict__ acc /* [0]=deno_sum [1]=cono_sum */)
{
    const int wave = threadIdx.x >> 6;
    const int lane = threadIdx.x & 63;
    const int row  = blockIdx.x * 4 + wave;

    __shared__ float blk[2];
    if (threadIdx.x == 0) { blk[0] = 0.f; blk[1] = 0.f; }
    __syncthreads();

    // strided per-lane elements: e = lane + 64*j, j=0..4 (covers 300)
    float cv[5], ev[5];
    int e[5];
    const float* cvp = center_v + (size_t)row * EMBED;
    const float* evp = enc + (size_t)row * HIDDEN;
    #pragma unroll
    for (int j = 0; j < 5; ++j) {
        e[j] = lane + 64 * j;
        const bool ok = e[j] < EMBED;
        cv[j] = ok ? cvp[e[j]] : 0.f;
        ev[j] = ok ? evp[e[j]] : 0.f;
    }

    // logit partials
    float p0 = 0.f, p1 = 0.f;
    #pragma unroll
    for (int j = 0; j < 5; ++j) {
        if (e[j] < HIDDEN) {
            p0 = fmaf(ev[j], W_cls[e[j]], p0);
            p1 = fmaf(ev[j], W_cls[HIDDEN + e[j]], p1);
        }
    }

    // positive context dot partial
    const float* ctxp = context_emb + (size_t)ctx_ids[row] * EMBED;
    float ps = 0.f;
    #pragma unroll
    for (int j = 0; j < 5; ++j)
        if (e[j] < EMBED) ps = fmaf(cv[j], ctxp[e[j]], ps);

    // negative dots partials
    float ns[K_NEG];
    #pragma unroll
    for (int k = 0; k < K_NEG; ++k) {
        const float* np_ = context_emb + (size_t)neg_ids[row * K_NEG + k] * EMBED;
        float s = 0.f;
        #pragma unroll
        for (int j = 0; j < 5; ++j)
            if (e[j] < EMBED) s = fmaf(cv[j], np_[e[j]], s);
        ns[k] = s;
    }

    // reductions
    p0 = wave_red(p0); p1 = wave_red(p1); ps = wave_red(ps);
    #pragma unroll
    for (int k = 0; k < K_NEG; ++k) ns[k] = wave_red(ns[k]);

    if (lane == 0) {
        const float l0 = p0 + b_cls[0];
        const float l1 = p1 + b_cls[1];
        const float m  = fmaxf(l0, l1);
        const float lse = m + logf(expf(l0 - m) + expf(l1 - m));
        const float nll = lse - (labels[row] ? l1 : l0);

        float s = fminf(10.f, fmaxf(-10.f, ps));
        float deno = softplusf(-s);        // -log_sigmoid(pos_score)
        #pragma unroll
        for (int k = 0; k < K_NEG; ++k) {
            const float t = fminf(10.f, fmaxf(-10.f, ns[k]));
            deno += softplusf(t);          // -log_sigmoid(-neg_score)
        }
        atomicAdd(&blk[0], deno);
        atomicAdd(&blk[1], nll);
    }
    __syncthreads();
    if (threadIdx.x == 0) {
        atomicAdd(&acc[0], blk[0]);
        atomicAdd(&acc[1], blk[1]);
    }
}

__global__ void finalize_kernel(const float* __restrict__ acc, float* __restrict__ out) {
    const float inv = 1.0f / (float)BATCH;
    float deno = acc[0] * inv;
    float cono = acc[1] * inv;
    deno = fminf(10.f, fmaxf(EPSV, deno));
    cono = fminf(10.f, fmaxf(EPSV, cono));
    const float encl = fmaxf(EPSV, deno + cono);
    out[0] = encl; out[1] = deno; out[2] = cono;
}

extern "C" void kernel_launch(void* const* d_in, const int* in_sizes, int n_in,
                              void* d_out, int out_size, void* d_ws, size_t ws_size,
                              hipStream_t stream)
{
    const int*   cids  = (const int*)d_in[0];
    const int*   ctx   = (const int*)d_in[1];
    const int*   neg   = (const int*)d_in[2];
    const int*   lab   = (const int*)d_in[3];
    const float* cemb  = (const float*)d_in[4];
    const float* xemb  = (const float*)d_in[5];
    const float* W_enc = (const float*)d_in[6];
    const float* b_enc = (const float*)d_in[7];
    const float* W_dec = (const float*)d_in[8];
    const float* b_dec = (const float*)d_in[9];
    const float* W_cls = (const float*)d_in[10];
    const float* b_cls = (const float*)d_in[11];
    float* out = (float*)d_out;

    float* enc = (float*)d_ws;                          // [BATCH, HIDDEN]
    float* cv  = enc + (size_t)BATCH * HIDDEN;          // [BATCH, EMBED]
    float* acc = cv  + (size_t)BATCH * EMBED;           // [2]

    hipMemsetAsync(acc, 0, 2 * sizeof(float), stream);

    dim3 grid1((HIDDEN + 63) / 64, BATCH / 64);         // (5, 512)
    gemm_at_kernel<true><<<grid1, 256, 0, stream>>>(cemb, cids, W_enc, b_enc,
                                                    enc, BATCH, HIDDEN, EMBED);
    dim3 grid2((EMBED + 63) / 64, BATCH / 64);          // (5, 512)
    gemm_at_kernel<false><<<grid2, 256, 0, stream>>>(enc, nullptr, W_dec, b_dec,
                                                     cv, BATCH, EMBED, HIDDEN);
    loss_kernel<<<BATCH / 4, 256, 0, stream>>>(enc, cv, ctx, neg, lab, xemb,
                                               W_cls, b_cls, acc);
    finalize_kernel<<<1, 1, 0, stream>>>(acc, out);
}

// Round 2
// 524.674 us; speedup vs baseline: 1.2637x; 1.2637x over previous
//
#include <hip/hip_runtime.h>
#include <math.h>

#define VOCAB   100000
#define EMBED   300
#define HIDDEN  300
#define BATCH   32768
#define K_NEG   10
#define EPSV    1e-5f

#define KPAD    320          // 300 padded to multiple of 32 (MFMA K)
#define NPAD    384          // weight rows padded to 3*128 (N tiles)
#define CV_STRIDE 304        // center_v bf16 row stride (8B-aligned ushort4)

typedef __attribute__((ext_vector_type(8))) short  short8;
typedef __attribute__((ext_vector_type(4))) float  f32x4;

__device__ inline float b2f(unsigned short u) {
    union { unsigned int i; float f; } v; v.i = ((unsigned int)u) << 16; return v.f;
}
__device__ inline unsigned short f2b(float f) {
    union { float f; unsigned int i; } v; v.f = f;
    unsigned int r = v.i + 0x7FFFu + ((v.i >> 16) & 1u);   // RNE
    return (unsigned short)(r >> 16);
}

// ---------------------------------------------------------------------------
// Pack weights: W[300,300] f32 -> Wp[NPAD,KPAD] bf16, zero-padded.
// Two matrices in one launch. 8 cols per thread.
// ---------------------------------------------------------------------------
__global__ __launch_bounds__(256)
void pack_w_kernel(const float* __restrict__ W0, const float* __restrict__ W1,
                   unsigned short* __restrict__ P0, unsigned short* __restrict__ P1)
{
    const int gid = blockIdx.x * 256 + threadIdx.x;       // 2*NPAD*40 threads
    const int mat = gid / (NPAD * 40);
    const int rem = gid - mat * (NPAD * 40);
    const int r   = rem / 40;
    const int c8  = (rem - r * 40) * 8;
    const float* src = mat ? W1 : W0;
    unsigned short* dst = mat ? P1 : P0;

    unsigned short t[8];
    #pragma unroll
    for (int j = 0; j < 8; ++j) {
        const int c = c8 + j;
        t[j] = (r < 300 && c < 300) ? f2b(src[r * 300 + c]) : (unsigned short)0;
    }
    *(uint4*)(dst + (size_t)r * KPAD + c8) = *(const uint4*)t;
}

// ---------------------------------------------------------------------------
// Gather + convert: emb_bf16[row, :] = bf16(center_emb[cids[row], :]), pad 0.
// ---------------------------------------------------------------------------
__global__ __launch_bounds__(256)
void pack_emb_kernel(const float* __restrict__ emb, const int* __restrict__ ids,
                     unsigned short* __restrict__ out)
{
    const int gid = blockIdx.x * 256 + threadIdx.x;       // BATCH*40 threads
    const int row = gid / 40;
    const int c8  = (gid - row * 40) * 8;
    const int id  = ids[row];
    const float* src = emb + (size_t)id * 300;

    unsigned short t[8];
    if (c8 + 7 < 300) {
        float4 a = *(const float4*)(src + c8);
        float4 b = *(const float4*)(src + c8 + 4);
        t[0]=f2b(a.x); t[1]=f2b(a.y); t[2]=f2b(a.z); t[3]=f2b(a.w);
        t[4]=f2b(b.x); t[5]=f2b(b.y); t[6]=f2b(b.z); t[7]=f2b(b.w);
    } else {
        #pragma unroll
        for (int j = 0; j < 8; ++j) {
            const int c = c8 + j;
            t[j] = (c < 300) ? f2b(src[c]) : (unsigned short)0;
        }
    }
    *(uint4*)(out + (size_t)row * KPAD + c8) = *(const uint4*)t;
}

// ---------------------------------------------------------------------------
// MFMA bf16 GEMM: C[m,n] = sum_k A[m,k]*B[n,k] + bias[n]
// A: [BATCH, KPAD] bf16;  B: [NPAD, KPAD] bf16 (zero-padded rows/cols)
// 128x128 block tile, 4 waves, each wave 4x4 grid of 16x16x32 MFMA tiles.
// Output bf16 with stride OSTRIDE; n<300 gets bias; PAD_ZERO writes 0 for
// n in [300, 320) (needed when output feeds the next GEMM's K).
// ---------------------------------------------------------------------------
template <int OSTRIDE, bool PAD_ZERO>
__global__ __launch_bounds__(256)
void mfma_gemm_kernel(const unsigned short* __restrict__ A,
                      const unsigned short* __restrict__ B,
                      const float* __restrict__ bias,
                      unsigned short* __restrict__ C)
{
    __shared__ unsigned short As[128][40];   // 32 bf16 + 8 pad (80 B stride)
    __shared__ unsigned short Bs[128][40];

    const int tid  = threadIdx.x;
    const int wave = tid >> 6;
    const int lane = tid & 63;
    const int m0 = blockIdx.y * 128;
    const int n0 = blockIdx.x * 128;

    const int wr = (wave & 1) * 64;          // wave row base in tile
    const int wc = (wave >> 1) * 64;         // wave col base in tile
    const int fr = lane & 15;                // fragment row/col
    const int fq = lane >> 4;                // quad

    const int lrow = tid >> 1;               // staging row 0..127
    const int lseg = (tid & 1) * 2;          // staging segments {0,1} or {2,3}

    f32x4 acc[4][4] = {};

    const unsigned short* aRow = A + (size_t)(m0 + lrow) * KPAD + lseg * 8;
    const unsigned short* bRow = B + (size_t)(n0 + lrow) * KPAD + lseg * 8;

    for (int k0 = 0; k0 < KPAD; k0 += 32) {
        uint4 a0 = *(const uint4*)(aRow + k0);
        uint4 a1 = *(const uint4*)(aRow + k0 + 8);
        uint4 b0 = *(const uint4*)(bRow + k0);
        uint4 b1 = *(const uint4*)(bRow + k0 + 8);
        __syncthreads();
        *(uint4*)&As[lrow][lseg * 8]     = a0;
        *(uint4*)&As[lrow][lseg * 8 + 8] = a1;
        *(uint4*)&Bs[lrow][lseg * 8]     = b0;
        *(uint4*)&Bs[lrow][lseg * 8 + 8] = b1;
        __syncthreads();

        short8 af[4], bf[4];
        #pragma unroll
        for (int i = 0; i < 4; ++i)
            af[i] = *(const short8*)&As[wr + i * 16 + fr][fq * 8];
        #pragma unroll
        for (int j = 0; j < 4; ++j)
            bf[j] = *(const short8*)&Bs[wc + j * 16 + fr][fq * 8];
        #pragma unroll
        for (int i = 0; i < 4; ++i)
            #pragma unroll
            for (int j = 0; j < 4; ++j)
                acc[i][j] = __builtin_amdgcn_mfma_f32_16x16x32_bf16(
                    af[i], bf[j], acc[i][j], 0, 0, 0);
    }

    // Epilogue: D[m = fq*4 + r][n = fr] per 16x16 tile.
    #pragma unroll
    for (int i = 0; i < 4; ++i) {
        #pragma unroll
        for (int r = 0; r < 4; ++r) {
            const int m = m0 + wr + i * 16 + fq * 4 + r;
            unsigned short* crow = C + (size_t)m * OSTRIDE;
            #pragma unroll
            for (int j = 0; j < 4; ++j) {
                const int n = n0 + wc + j * 16 + fr;
                if (n < 300) {
                    crow[n] = f2b(acc[i][j][r] + bias[n]);
                } else if (PAD_ZERO && n < KPAD) {
                    crow[n] = 0;
                }
            }
        }
    }
}

// ---------------------------------------------------------------------------
// Per-row loss, one wave per row, fully vectorized 16B loads.
// ---------------------------------------------------------------------------
__device__ inline float wave_red(float v) {
    #pragma unroll
    for (int o = 32; o; o >>= 1) v += __shfl_down(v, o);
    return v;
}
__device__ inline float softplusf(float x) {
    return x > 0.f ? x + log1pf(expf(-x)) : log1pf(expf(x));
}
__device__ inline float4 bf4(ushort4 u) {
    return make_float4(b2f(u.x), b2f(u.y), b2f(u.z), b2f(u.w));
}
__device__ inline float dot4(float4 a, float4 b, float s) {
    s = fmaf(a.x, b.x, s); s = fmaf(a.y, b.y, s);
    s = fmaf(a.z, b.z, s); s = fmaf(a.w, b.w, s);
    return s;
}

__global__ __launch_bounds__(256)
void loss_kernel(const unsigned short* __restrict__ encb,
                 const unsigned short* __restrict__ cvb,
                 const int* __restrict__ ctx_ids, const int* __restrict__ neg_ids,
                 const int* __restrict__ labels,
                 const float* __restrict__ context_emb,
                 const float* __restrict__ W_cls, const float* __restrict__ b_cls,
                 float* __restrict__ acc)
{
    const int wave = threadIdx.x >> 6;
    const int lane = threadIdx.x & 63;
    const int row  = blockIdx.x * 4 + wave;
    const bool tail = lane < 11;   // second segment covers floats 256..299

    __shared__ float blk[2];
    if (threadIdx.x == 0) { blk[0] = 0.f; blk[1] = 0.f; }
    __syncthreads();

    const float4 Z = make_float4(0.f, 0.f, 0.f, 0.f);

    // center_v row (bf16)
    const unsigned short* cvp = cvb + (size_t)row * CV_STRIDE;
    const float4 cv0 = bf4(*(const ushort4*)(cvp + 4 * lane));
    const float4 cv1 = tail ? bf4(*(const ushort4*)(cvp + 256 + 4 * lane)) : Z;

    // enc row (bf16) + classifier weights (f32)
    const unsigned short* evp = encb + (size_t)row * KPAD;
    const float4 ev0 = bf4(*(const ushort4*)(evp + 4 * lane));
    const float4 ev1 = tail ? bf4(*(const ushort4*)(evp + 256 + 4 * lane)) : Z;

    const float4 w00 = *(const float4*)(W_cls + 4 * lane);
    const float4 w01 = tail ? *(const float4*)(W_cls + 256 + 4 * lane) : Z;
    const float4 w10 = *(const float4*)(W_cls + 300 + 4 * lane);
    const float4 w11 = tail ? *(const float4*)(W_cls + 300 + 256 + 4 * lane) : Z;

    // gather ids
    const int cid = ctx_ids[row];
    const int lb  = labels[row];
    int nid[K_NEG];
    #pragma unroll
    for (int k = 0; k < K_NEG; ++k) nid[k] = neg_ids[row * K_NEG + k];

    // positive context row
    const float* ctxp = context_emb + (size_t)cid * 300;
    const float4 g0 = *(const float4*)(ctxp + 4 * lane);
    const float4 g1 = tail ? *(const float4*)(ctxp + 256 + 4 * lane) : Z;

    // all negative rows into registers (keeps ~20 16B loads in flight)
    float4 n0[K_NEG], n1[K_NEG];
    #pragma unroll
    for (int k = 0; k < K_NEG; ++k) {
        const float* np_ = context_emb + (size_t)nid[k] * 300;
        n0[k] = *(const float4*)(np_ + 4 * lane);
        n1[k] = tail ? *(const float4*)(np_ + 256 + 4 * lane) : Z;
    }

    float p0 = dot4(ev1, w01, dot4(ev0, w00, 0.f));
    float p1 = dot4(ev1, w11, dot4(ev0, w10, 0.f));
    float ps = dot4(cv1, g1,  dot4(cv0, g0,  0.f));
    float ns[K_NEG];
    #pragma unroll
    for (int k = 0; k < K_NEG; ++k)
        ns[k] = dot4(cv1, n1[k], dot4(cv0, n0[k], 0.f));

    p0 = wave_red(p0); p1 = wave_red(p1); ps = wave_red(ps);
    #pragma unroll
    for (int k = 0; k < K_NEG; ++k) ns[k] = wave_red(ns[k]);

    if (lane == 0) {
        const float l0 = p0 + b_cls[0];
        const float l1 = p1 + b_cls[1];
        const float mx = fmaxf(l0, l1);
        const float lse = mx + logf(expf(l0 - mx) + expf(l1 - mx));
        const float nll = lse - (lb ? l1 : l0);

        float s = fminf(10.f, fmaxf(-10.f, ps));
        float deno = softplusf(-s);
        #pragma unroll
        for (int k = 0; k < K_NEG; ++k) {
            const float t = fminf(10.f, fmaxf(-10.f, ns[k]));
            deno += softplusf(t);
        }
        atomicAdd(&blk[0], deno);
        atomicAdd(&blk[1], nll);
    }
    __syncthreads();
    if (threadIdx.x == 0) {
        atomicAdd(&acc[0], blk[0]);
        atomicAdd(&acc[1], blk[1]);
    }
}

__global__ void finalize_kernel(const float* __restrict__ acc, float* __restrict__ out) {
    const float inv = 1.0f / (float)BATCH;
    float deno = acc[0] * inv;
    float cono = acc[1] * inv;
    deno = fminf(10.f, fmaxf(EPSV, deno));
    cono = fminf(10.f, fmaxf(EPSV, cono));
    out[0] = fmaxf(EPSV, deno + cono);
    out[1] = deno;
    out[2] = cono;
}

extern "C" void kernel_launch(void* const* d_in, const int* in_sizes, int n_in,
                              void* d_out, int out_size, void* d_ws, size_t ws_size,
                              hipStream_t stream)
{
    const int*   cids  = (const int*)d_in[0];
    const int*   ctx   = (const int*)d_in[1];
    const int*   neg   = (const int*)d_in[2];
    const int*   lab   = (const int*)d_in[3];
    const float* cemb  = (const float*)d_in[4];
    const float* xemb  = (const float*)d_in[5];
    const float* W_enc = (const float*)d_in[6];
    const float* b_enc = (const float*)d_in[7];
    const float* W_dec = (const float*)d_in[8];
    const float* b_dec = (const float*)d_in[9];
    const float* W_cls = (const float*)d_in[10];
    const float* b_cls = (const float*)d_in[11];
    float* out = (float*)d_out;

    // workspace layout (all 16B aligned)
    unsigned short* emb_b  = (unsigned short*)d_ws;                 // [BATCH][KPAD]
    unsigned short* wenc_b = emb_b  + (size_t)BATCH * KPAD;         // [NPAD][KPAD]
    unsigned short* wdec_b = wenc_b + (size_t)NPAD * KPAD;          // [NPAD][KPAD]
    unsigned short* enc_b  = wdec_b + (size_t)NPAD * KPAD;          // [BATCH][KPAD]
    unsigned short* cv_b   = enc_b  + (size_t)BATCH * KPAD;         // [BATCH][CV_STRIDE]
    float*          acc    = (float*)(cv_b + (size_t)BATCH * CV_STRIDE);

    hipMemsetAsync(acc, 0, 2 * sizeof(float), stream);

    pack_w_kernel<<<(2 * NPAD * 40) / 256, 256, 0, stream>>>(W_enc, W_dec, wenc_b, wdec_b);
    pack_emb_kernel<<<(BATCH * 40) / 256, 256, 0, stream>>>(cemb, cids, emb_b);

    dim3 ggrid(3, BATCH / 128);   // N tiles {0,128,256}, 256 M tiles
    mfma_gemm_kernel<KPAD, true><<<ggrid, 256, 0, stream>>>(emb_b, wenc_b, b_enc, enc_b);
    mfma_gemm_kernel<CV_STRIDE, false><<<ggrid, 256, 0, stream>>>(enc_b, wdec_b, b_dec, cv_b);

    loss_kernel<<<BATCH / 4, 256, 0, stream>>>(enc_b, cv_b, ctx, neg, lab, xemb,
                                               W_cls, b_cls, acc);
    finalize_kernel<<<1, 1, 0, stream>>>(acc, out);
}

// Round 3
// 424.841 us; speedup vs baseline: 1.5606x; 1.2350x over previous
//
#include <hip/hip_runtime.h>
#include <math.h>

#define VOCAB   100000
#define EMBED   300
#define HIDDEN  300
#define BATCH   32768
#define K_NEG   10
#define EPSV    1e-5f

#define KPAD    320          // 300 padded to multiple of 32 (MFMA K)
#define NPAD    384          // weight rows padded to 3*128 (N tiles)
#define CV_STRIDE 304        // center_v / ctx bf16 row stride (16B-aligned)
#define NBUCKET 512

typedef __attribute__((ext_vector_type(8))) short  short8;
typedef __attribute__((ext_vector_type(4))) float  f32x4;

__device__ inline float b2f(unsigned short u) {
    union { unsigned int i; float f; } v; v.i = ((unsigned int)u) << 16; return v.f;
}
__device__ inline unsigned short f2b(float f) {
    union { float f; unsigned int i; } v; v.f = f;
    unsigned int r = v.i + 0x7FFFu + ((v.i >> 16) & 1u);   // RNE
    return (unsigned short)(r >> 16);
}
__device__ inline float wave_red(float v) {
    #pragma unroll
    for (int o = 32; o; o >>= 1) v += __shfl_down(v, o);
    return v;
}
__device__ inline float softplusf(float x) {
    return x > 0.f ? x + log1pf(expf(-x)) : log1pf(expf(x));
}
__device__ inline float4 bf4(ushort4 u) {
    return make_float4(b2f(u.x), b2f(u.y), b2f(u.z), b2f(u.w));
}
__device__ inline float dot4(float4 a, float4 b, float s) {
    s = fmaf(a.x, b.x, s); s = fmaf(a.y, b.y, s);
    s = fmaf(a.z, b.z, s); s = fmaf(a.w, b.w, s);
    return s;
}
// unpack uint (2 packed bf16) -> 2 floats
__device__ inline void up2(unsigned int u, float& lo, float& hi) {
    union { unsigned int i; float f; } a, b;
    a.i = u << 16; b.i = u & 0xFFFF0000u;
    lo = a.f; hi = b.f;
}

// ---------------------------------------------------------------------------
// Pack weights: W[300,300] f32 -> Wp[NPAD,KPAD] bf16, zero-padded.
// ---------------------------------------------------------------------------
__global__ __launch_bounds__(256)
void pack_w_kernel(const float* __restrict__ W0, const float* __restrict__ W1,
                   unsigned short* __restrict__ P0, unsigned short* __restrict__ P1)
{
    const int gid = blockIdx.x * 256 + threadIdx.x;       // 2*NPAD*40 threads
    const int mat = gid / (NPAD * 40);
    const int rem = gid - mat * (NPAD * 40);
    const int r   = rem / 40;
    const int c8  = (rem - r * 40) * 8;
    const float* src = mat ? W1 : W0;
    unsigned short* dst = mat ? P1 : P0;

    unsigned short t[8];
    #pragma unroll
    for (int j = 0; j < 8; ++j) {
        const int c = c8 + j;
        t[j] = (r < 300 && c < 300) ? f2b(src[r * 300 + c]) : (unsigned short)0;
    }
    *(uint4*)(dst + (size_t)r * KPAD + c8) = *(const uint4*)t;
}

// ---------------------------------------------------------------------------
// Gather + convert center rows: emb_bf16[row,:] = bf16(center_emb[cids[row],:])
// ---------------------------------------------------------------------------
__global__ __launch_bounds__(256)
void pack_emb_kernel(const float* __restrict__ emb, const int* __restrict__ ids,
                     unsigned short* __restrict__ out)
{
    const int gid = blockIdx.x * 256 + threadIdx.x;       // BATCH*40 threads
    const int row = gid / 40;
    const int c8  = (gid - row * 40) * 8;
    const int id  = ids[row];
    const float* src = emb + (size_t)id * 300;

    unsigned short t[8];
    if (c8 + 7 < 300) {
        float4 a = *(const float4*)(src + c8);
        float4 b = *(const float4*)(src + c8 + 4);
        t[0]=f2b(a.x); t[1]=f2b(a.y); t[2]=f2b(a.z); t[3]=f2b(a.w);
        t[4]=f2b(b.x); t[5]=f2b(b.y); t[6]=f2b(b.z); t[7]=f2b(b.w);
    } else {
        #pragma unroll
        for (int j = 0; j < 8; ++j) {
            const int c = c8 + j;
            t[j] = (c < 300) ? f2b(src[c]) : (unsigned short)0;
        }
    }
    *(uint4*)(out + (size_t)row * KPAD + c8) = *(const uint4*)t;
}

// ---------------------------------------------------------------------------
// Pack context_emb f32[100000,300] -> bf16[100000, CV_STRIDE] (zero pad tail)
// ---------------------------------------------------------------------------
__global__ __launch_bounds__(256)
void pack_ctx_kernel(const float* __restrict__ x, unsigned short* __restrict__ out)
{
    const int gid = blockIdx.x * 256 + threadIdx.x;       // VOCAB*38 threads
    if (gid >= VOCAB * 38) return;
    const int row = gid / 38;
    const int c8  = (gid - row * 38) * 8;
    const float* src = x + (size_t)row * 300;

    unsigned short t[8];
    if (c8 + 7 < 300) {
        float4 a = *(const float4*)(src + c8);
        float4 b = *(const float4*)(src + c8 + 4);
        t[0]=f2b(a.x); t[1]=f2b(a.y); t[2]=f2b(a.z); t[3]=f2b(a.w);
        t[4]=f2b(b.x); t[5]=f2b(b.y); t[6]=f2b(b.z); t[7]=f2b(b.w);
    } else {
        #pragma unroll
        for (int j = 0; j < 8; ++j) {
            const int c = c8 + j;
            t[j] = (c < 300) ? f2b(src[c]) : (unsigned short)0;
        }
    }
    *(uint4*)(out + (size_t)row * CV_STRIDE + c8) = *(const uint4*)t;
}

// ---------------------------------------------------------------------------
// MFMA bf16 GEMM (unchanged from R2, except PAD_ZERO pads to OSTRIDE).
// ---------------------------------------------------------------------------
template <int OSTRIDE, bool PAD_ZERO>
__global__ __launch_bounds__(256)
void mfma_gemm_kernel(const unsigned short* __restrict__ A,
                      const unsigned short* __restrict__ B,
                      const float* __restrict__ bias,
                      unsigned short* __restrict__ C)
{
    __shared__ unsigned short As[128][40];
    __shared__ unsigned short Bs[128][40];

    const int tid  = threadIdx.x;
    const int wave = tid >> 6;
    const int lane = tid & 63;
    const int m0 = blockIdx.y * 128;
    const int n0 = blockIdx.x * 128;

    const int wr = (wave & 1) * 64;
    const int wc = (wave >> 1) * 64;
    const int fr = lane & 15;
    const int fq = lane >> 4;

    const int lrow = tid >> 1;
    const int lseg = (tid & 1) * 2;

    f32x4 acc[4][4] = {};

    const unsigned short* aRow = A + (size_t)(m0 + lrow) * KPAD + lseg * 8;
    const unsigned short* bRow = B + (size_t)(n0 + lrow) * KPAD + lseg * 8;

    for (int k0 = 0; k0 < KPAD; k0 += 32) {
        uint4 a0 = *(const uint4*)(aRow + k0);
        uint4 a1 = *(const uint4*)(aRow + k0 + 8);
        uint4 b0 = *(const uint4*)(bRow + k0);
        uint4 b1 = *(const uint4*)(bRow + k0 + 8);
        __syncthreads();
        *(uint4*)&As[lrow][lseg * 8]     = a0;
        *(uint4*)&As[lrow][lseg * 8 + 8] = a1;
        *(uint4*)&Bs[lrow][lseg * 8]     = b0;
        *(uint4*)&Bs[lrow][lseg * 8 + 8] = b1;
        __syncthreads();

        short8 af[4], bfr[4];
        #pragma unroll
        for (int i = 0; i < 4; ++i)
            af[i] = *(const short8*)&As[wr + i * 16 + fr][fq * 8];
        #pragma unroll
        for (int j = 0; j < 4; ++j)
            bfr[j] = *(const short8*)&Bs[wc + j * 16 + fr][fq * 8];
        #pragma unroll
        for (int i = 0; i < 4; ++i)
            #pragma unroll
            for (int j = 0; j < 4; ++j)
                acc[i][j] = __builtin_amdgcn_mfma_f32_16x16x32_bf16(
                    af[i], bfr[j], acc[i][j], 0, 0, 0);
    }

    #pragma unroll
    for (int i = 0; i < 4; ++i) {
        #pragma unroll
        for (int r = 0; r < 4; ++r) {
            const int m = m0 + wr + i * 16 + fq * 4 + r;
            unsigned short* crow = C + (size_t)m * OSTRIDE;
            #pragma unroll
            for (int j = 0; j < 4; ++j) {
                const int n = n0 + wc + j * 16 + fr;
                if (n < 300) {
                    crow[n] = f2b(acc[i][j][r] + bias[n]);
                } else if (PAD_ZERO && n < OSTRIDE) {
                    crow[n] = 0;
                }
            }
        }
    }
}

// ---------------------------------------------------------------------------
// CE kernel: one wave per row (streaming, no gathers).
// ---------------------------------------------------------------------------
__global__ __launch_bounds__(256)
void ce_kernel(const unsigned short* __restrict__ encb,
               const int* __restrict__ labels,
               const float* __restrict__ W_cls, const float* __restrict__ b_cls,
               float* __restrict__ cono_buckets)
{
    const int wave = threadIdx.x >> 6;
    const int lane = threadIdx.x & 63;
    const int row  = blockIdx.x * 4 + wave;
    const bool tail = lane < 11;

    __shared__ float blk;
    if (threadIdx.x == 0) blk = 0.f;
    __syncthreads();

    const float4 Z = make_float4(0.f, 0.f, 0.f, 0.f);
    const unsigned short* evp = encb + (size_t)row * KPAD;
    const float4 ev0 = bf4(*(const ushort4*)(evp + 4 * lane));
    const float4 ev1 = tail ? bf4(*(const ushort4*)(evp + 256 + 4 * lane)) : Z;

    const float4 w00 = *(const float4*)(W_cls + 4 * lane);
    const float4 w01 = tail ? *(const float4*)(W_cls + 256 + 4 * lane) : Z;
    const float4 w10 = *(const float4*)(W_cls + 300 + 4 * lane);
    const float4 w11 = tail ? *(const float4*)(W_cls + 300 + 256 + 4 * lane) : Z;

    float p0 = dot4(ev1, w01, dot4(ev0, w00, 0.f));
    float p1 = dot4(ev1, w11, dot4(ev0, w10, 0.f));
    p0 = wave_red(p0); p1 = wave_red(p1);

    if (lane == 0) {
        const float l0 = p0 + b_cls[0];
        const float l1 = p1 + b_cls[1];
        const float mx = fmaxf(l0, l1);
        const float lse = mx + logf(expf(l0 - mx) + expf(l1 - mx));
        const float nll = lse - (labels[row] ? l1 : l0);
        atomicAdd(&blk, nll);
    }
    __syncthreads();
    if (threadIdx.x == 0)
        atomicAdd(&cono_buckets[blockIdx.x & (NBUCKET - 1)], blk);
}

// ---------------------------------------------------------------------------
// Score kernel: one wave per (row, score-group) unit; 3 groups per row:
//   g0 = {pos, n0, n1, n2}, g1 = {n3..n6}, g2 = {n7, n8, n9}
// BF16CTX: gather from packed bf16 ctx (1 load/row, lanes<38) else f32
// (1 float4 load/row-segment, lanes<75). All gather loads independent.
// ---------------------------------------------------------------------------
template <bool BF16CTX>
__global__ __launch_bounds__(256)
void score_kernel(const unsigned short* __restrict__ cvb,
                  const int* __restrict__ ctx_ids, const int* __restrict__ neg_ids,
                  const unsigned short* __restrict__ ctxb,
                  const float* __restrict__ ctxf,
                  float* __restrict__ deno_buckets)
{
    const int wave = threadIdx.x >> 6;
    const int lane = threadIdx.x & 63;
    const int unit = blockIdx.x * 4 + wave;
    const int row  = unit / 3;
    const int g    = unit - row * 3;

    __shared__ float blk;
    if (threadIdx.x == 0) blk = 0.f;
    __syncthreads();

    int ids[4];
    const int b = row * K_NEG;
    bool hasPos = false; int nscore = 4;
    if (g == 0) {
        hasPos = true;
        ids[0] = ctx_ids[row];
        ids[1] = neg_ids[b + 0]; ids[2] = neg_ids[b + 1]; ids[3] = neg_ids[b + 2];
    } else if (g == 1) {
        ids[0] = neg_ids[b + 3]; ids[1] = neg_ids[b + 4];
        ids[2] = neg_ids[b + 5]; ids[3] = neg_ids[b + 6];
    } else {
        nscore = 3;
        ids[0] = neg_ids[b + 7]; ids[1] = neg_ids[b + 8];
        ids[2] = neg_ids[b + 9]; ids[3] = neg_ids[b + 9];
    }

    float ds[4];
    const unsigned short* cvp = cvb + (size_t)row * CV_STRIDE;

    if (BF16CTX) {
        const bool act = lane < 38;                 // 38*8 = 304 cols
        const uint4 zero = make_uint4(0,0,0,0);
        uint4 cvu = act ? *(const uint4*)(cvp + 8 * lane) : zero;
        uint4 gv[4];
        #pragma unroll
        for (int j = 0; j < 4; ++j)
            gv[j] = act ? *(const uint4*)(ctxb + (size_t)ids[j] * CV_STRIDE + 8 * lane)
                        : zero;
        float cvf[8];
        up2(cvu.x, cvf[0], cvf[1]); up2(cvu.y, cvf[2], cvf[3]);
        up2(cvu.z, cvf[4], cvf[5]); up2(cvu.w, cvf[6], cvf[7]);
        #pragma unroll
        for (int j = 0; j < 4; ++j) {
            float gf[8];
            up2(gv[j].x, gf[0], gf[1]); up2(gv[j].y, gf[2], gf[3]);
            up2(gv[j].z, gf[4], gf[5]); up2(gv[j].w, gf[6], gf[7]);
            float s = 0.f;
            #pragma unroll
            for (int e = 0; e < 8; ++e) s = fmaf(cvf[e], gf[e], s);
            ds[j] = s;
        }
    } else {
        const bool act = lane < 75;                 // 75*4 = 300 cols
        const float4 Z = make_float4(0.f,0.f,0.f,0.f);
        const ushort4 uz = {0,0,0,0};
        float4 cv = bf4(act ? *(const ushort4*)(cvp + 4 * lane) : uz);
        float4 gv[4];
        #pragma unroll
        for (int j = 0; j < 4; ++j)
            gv[j] = act ? *(const float4*)(ctxf + (size_t)ids[j] * 300 + 4 * lane) : Z;
        #pragma unroll
        for (int j = 0; j < 4; ++j) ds[j] = dot4(cv, gv[j], 0.f);
    }

    #pragma unroll
    for (int j = 0; j < 4; ++j) ds[j] = wave_red(ds[j]);

    if (lane == 0) {
        float local = 0.f;
        #pragma unroll
        for (int j = 0; j < 4; ++j) {
            if (j < nscore) {
                float s = fminf(10.f, fmaxf(-10.f, ds[j]));
                local += softplusf((hasPos && j == 0) ? -s : s);
            }
        }
        atomicAdd(&blk, local);
    }
    __syncthreads();
    if (threadIdx.x == 0)
        atomicAdd(&deno_buckets[blockIdx.x & (NBUCKET - 1)], blk);
}

// ---------------------------------------------------------------------------
__global__ __launch_bounds__(256)
void finalize_kernel(const float* __restrict__ db, const float* __restrict__ cb,
                     float* __restrict__ out)
{
    const int t = threadIdx.x;
    float d = db[t] + db[t + 256];
    float c = cb[t] + cb[t + 256];
    d = wave_red(d); c = wave_red(c);
    __shared__ float sd[4], sc[4];
    if ((t & 63) == 0) { sd[t >> 6] = d; sc[t >> 6] = c; }
    __syncthreads();
    if (t == 0) {
        const float inv = 1.0f / (float)BATCH;
        float deno = (sd[0] + sd[1] + sd[2] + sd[3]) * inv;
        float cono = (sc[0] + sc[1] + sc[2] + sc[3]) * inv;
        deno = fminf(10.f, fmaxf(EPSV, deno));
        cono = fminf(10.f, fmaxf(EPSV, cono));
        out[0] = fmaxf(EPSV, deno + cono);
        out[1] = deno;
        out[2] = cono;
    }
}

extern "C" void kernel_launch(void* const* d_in, const int* in_sizes, int n_in,
                              void* d_out, int out_size, void* d_ws, size_t ws_size,
                              hipStream_t stream)
{
    const int*   cids  = (const int*)d_in[0];
    const int*   ctx   = (const int*)d_in[1];
    const int*   neg   = (const int*)d_in[2];
    const int*   lab   = (const int*)d_in[3];
    const float* cemb  = (const float*)d_in[4];
    const float* xemb  = (const float*)d_in[5];
    const float* W_enc = (const float*)d_in[6];
    const float* b_enc = (const float*)d_in[7];
    const float* W_dec = (const float*)d_in[8];
    const float* b_dec = (const float*)d_in[9];
    const float* W_cls = (const float*)d_in[10];
    const float* b_cls = (const float*)d_in[11];
    float* out = (float*)d_out;

    // workspace layout (all 16B aligned)
    unsigned short* emb_b  = (unsigned short*)d_ws;                 // [BATCH][KPAD]
    unsigned short* wenc_b = emb_b  + (size_t)BATCH * KPAD;
    unsigned short* wdec_b = wenc_b + (size_t)NPAD * KPAD;
    unsigned short* enc_b  = wdec_b + (size_t)NPAD * KPAD;          // [BATCH][KPAD]
    unsigned short* cv_b   = enc_b  + (size_t)BATCH * KPAD;         // [BATCH][CV_STRIDE]
    unsigned short* ctx_b  = cv_b   + (size_t)BATCH * CV_STRIDE;    // [VOCAB][CV_STRIDE]
    float* buckets = (float*)(ctx_b + (size_t)VOCAB * CV_STRIDE);   // 2*NBUCKET
    const size_t need = (char*)(buckets + 2 * NBUCKET) - (char*)d_ws;
    const bool bf16ctx = ws_size >= need;
    if (!bf16ctx)   // fallback layout: no ctx_b
        buckets = (float*)(cv_b + (size_t)BATCH * CV_STRIDE);
    float* db = buckets;
    float* cb = buckets + NBUCKET;

    hipMemsetAsync(buckets, 0, 2 * NBUCKET * sizeof(float), stream);

    pack_w_kernel<<<(2 * NPAD * 40) / 256, 256, 0, stream>>>(W_enc, W_dec, wenc_b, wdec_b);
    pack_emb_kernel<<<(BATCH * 40) / 256, 256, 0, stream>>>(cemb, cids, emb_b);
    if (bf16ctx)
        pack_ctx_kernel<<<(VOCAB * 38 + 255) / 256, 256, 0, stream>>>(xemb, ctx_b);

    dim3 ggrid(3, BATCH / 128);
    mfma_gemm_kernel<KPAD, true><<<ggrid, 256, 0, stream>>>(emb_b, wenc_b, b_enc, enc_b);
    mfma_gemm_kernel<CV_STRIDE, true><<<ggrid, 256, 0, stream>>>(enc_b, wdec_b, b_dec, cv_b);

    ce_kernel<<<BATCH / 4, 256, 0, stream>>>(enc_b, lab, W_cls, b_cls, cb);

    const int units = 3 * BATCH;
    if (bf16ctx)
        score_kernel<true><<<units / 4, 256, 0, stream>>>(cv_b, ctx, neg, ctx_b, nullptr, db);
    else
        score_kernel<false><<<units / 4, 256, 0, stream>>>(cv_b, ctx, neg, nullptr, xemb, db);

    finalize_kernel<<<1, 256, 0, stream>>>(db, cb, out);
}